// Round 3
// baseline (6145.982 us; speedup 1.0000x reference)
//
#include <hip/hip_runtime.h>
#include <hip/hip_fp16.h>

// Problem constants
#define TT 2048
#define II 1739
#define HN 256
#define H3 768

typedef _Float16 h8v __attribute__((ext_vector_type(8)));
typedef float f4v __attribute__((ext_vector_type(4)));

// C[M,N] = A[M,K] @ B[N,K]^T + bias1[n] + (n < b2lim ? bias2[n] : 0)
// 64x64 tile, 256 threads, 4x4 micro-tile per thread.
__global__ __launch_bounds__(256) void gemm_abt(
    const float* __restrict__ A, int M, int K,
    const float* __restrict__ B, int N,
    const float* __restrict__ bias1, const float* __restrict__ bias2, int b2lim,
    float* __restrict__ C) {
  __shared__ float As[16][64];
  __shared__ float Bs[16][64];
  const int tid = threadIdx.x;
  const int m0 = blockIdx.y * 64, n0 = blockIdx.x * 64;
  const int lr = tid >> 2;        // 0..63  (row within tile for loads)
  const int lk = (tid & 3) * 4;   // 0,4,8,12
  const int cx = tid & 15, cy = tid >> 4;
  float acc[4][4] = {};

  for (int k0 = 0; k0 < K; k0 += 16) {
#pragma unroll
    for (int i = 0; i < 4; ++i) {
      int k = k0 + lk + i;
      As[lk + i][lr] = (k < K) ? A[(size_t)(m0 + lr) * K + k] : 0.f;
      int bn = n0 + lr;
      Bs[lk + i][lr] = (k < K && bn < N) ? B[(size_t)bn * K + k] : 0.f;
    }
    __syncthreads();
#pragma unroll
    for (int k = 0; k < 16; ++k) {
      float4 av = *(const float4*)&As[k][cy * 4];
      float4 bv = *(const float4*)&Bs[k][cx * 4];
      const float aa[4] = {av.x, av.y, av.z, av.w};
      const float bb[4] = {bv.x, bv.y, bv.z, bv.w};
#pragma unroll
      for (int i = 0; i < 4; ++i)
#pragma unroll
        for (int j = 0; j < 4; ++j) acc[i][j] = fmaf(aa[i], bb[j], acc[i][j]);
    }
    __syncthreads();
  }
#pragma unroll
  for (int i = 0; i < 4; ++i) {
    int m = m0 + cy * 4 + i;
#pragma unroll
    for (int j = 0; j < 4; ++j) {
      int n = n0 + cx * 4 + j;
      if (n < N) {
        float b = bias1 ? bias1[n] : 0.f;
        if (bias2 && n < b2lim) b += bias2[n];
        C[(size_t)m * N + n] = acc[i][j] + b;
      }
    }
  }
}

// Sequential GRU scan on a single CU (1 block, 512 threads = 8 waves, 2 waves/EU).
// Matvec via v_mfma_f32_16x16x32_f16 with W_hh held as f16 A-fragments in
// AGPRs (192 regs/thread, MFMA reads AGPR natively -> no accvgpr copies).
// Wave wv owns row-tiles 6*wv..6*wv+5 (16 rows each). Broadcast-B: every lane
// loads the same h k-slice h[32*kc + 8*q .. +8] (q=lane>>4) so B[k][n]=h[k]
// for all n and every column of D equals W.h; k-sum done inside MFMA.
// D layout (verified): row = q*4 + reg, col = lane&15 -> lanes with
// (lane&15)==0 write float4 to hh.
__global__ __launch_bounds__(512) __attribute__((amdgpu_waves_per_eu(2, 2)))
void gru_seq(
    const float* __restrict__ xp,      // [T, 768]
    const float* __restrict__ Whh,     // [768, 256]
    const float* __restrict__ bhh,     // [768]
    const float* __restrict__ h0,      // [256] or nullptr (zeros)
    float* __restrict__ hs_out,        // [T, 256] or nullptr
    float* __restrict__ hT_out) {      // [256] or nullptr
  __shared__ _Float16 hbuf[HN];  // h as f16, linear
  __shared__ float hh[H3];

  const int tid = threadIdx.x;
  const int lane = tid & 63;
  const int wv = tid >> 6;
  const int q = lane >> 4;   // quad-row 0..3
  const int ml = lane & 15;  // row within 16-row tile

  // Load A-fragments: 6 tiles x 8 k-chunks, 8 f16 per lane each.
  // afrag[i][kc] holds W[96*wv + 16*i + ml][32*kc + 8*q + j], j=0..7.
  h8v afrag[6][8];
#pragma unroll
  for (int i = 0; i < 6; ++i) {
    const float* wr = Whh + (size_t)(96 * wv + 16 * i + ml) * HN + 8 * q;
#pragma unroll
    for (int kc = 0; kc < 8; ++kc) {
      const float* wp = wr + 32 * kc;
      float4 a = *(const float4*)wp;
      float4 b = *(const float4*)(wp + 4);
      afrag[i][kc] = h8v{(_Float16)a.x, (_Float16)a.y, (_Float16)a.z, (_Float16)a.w,
                         (_Float16)b.x, (_Float16)b.y, (_Float16)b.z, (_Float16)b.w};
    }
  }

  float hj = 0.f, bhn = 0.f;
  if (tid < HN) {
    hj = h0 ? h0[tid] : 0.f;
    bhn = bhh[2 * HN + tid];
    hbuf[tid] = (_Float16)hj;
  }
  __syncthreads();

  // Prefetch xp for step 0.
  float xr = 0.f, xz = 0.f, xn = 0.f;
  if (tid < HN) {
    const float* xpt = xp + tid;
    xr = xpt[0];
    xz = xpt[HN];
    xn = xpt[2 * HN];
  }

  for (int t = 0; t < TT; ++t) {
    // Prefetch next step's x-projection (consumed 1 full step later).
    float nxr = 0.f, nxz = 0.f, nxn = 0.f;
    if (tid < HN && t + 1 < TT) {
      const float* xpt = xp + (size_t)(t + 1) * H3 + tid;
      nxr = xpt[0];
      nxz = xpt[HN];
      nxn = xpt[2 * HN];
    }

    f4v acc[6];
#pragma unroll
    for (int i = 0; i < 6; ++i) acc[i] = f4v{0.f, 0.f, 0.f, 0.f};

    // Two phases of 4 k-chunks to cap live hv registers at 16.
#pragma unroll
    for (int ph = 0; ph < 2; ++ph) {
      h8v hv[4];
#pragma unroll
      for (int c = 0; c < 4; ++c)
        hv[c] = *(const h8v*)((const char*)hbuf + 64 * (ph * 4 + c) + 16 * q);
#pragma unroll
      for (int c = 0; c < 4; ++c) {
#pragma unroll
        for (int i = 0; i < 6; ++i)
          acc[i] = __builtin_amdgcn_mfma_f32_16x16x32_f16(afrag[i][ph * 4 + c], hv[c], acc[i], 0, 0, 0);
      }
    }

    // Write matvec results: lane ml==0 of each quad-row has rows q*4+0..3.
    if (ml == 0) {
#pragma unroll
      for (int i = 0; i < 6; ++i)
        *(f4v*)(hh + 96 * wv + 16 * i + 4 * q) = acc[i];
    }
    __syncthreads();

    // Gates (threads 0..255, one per hidden unit).
    if (tid < HN) {
      float r = 1.f / (1.f + __expf(-(xr + hh[tid])));
      float z = 1.f / (1.f + __expf(-(xz + hh[HN + tid])));
      float nv = 2.f / (1.f + __expf(-2.f * (xn + r * (hh[2 * HN + tid] + bhn)))) - 1.f;
      hj = (1.f - z) * nv + z * hj;
      if (hs_out) hs_out[(size_t)t * HN + tid] = hj;
      hbuf[tid] = (_Float16)hj;
    }
    xr = nxr; xz = nxz; xn = nxn;
    __syncthreads();
  }
  if (hT_out && tid < HN) hT_out[tid] = hj;
}

extern "C" void kernel_launch(void* const* d_in, const int* in_sizes, int n_in,
                              void* d_out, int out_size, void* d_ws, size_t ws_size,
                              hipStream_t stream) {
  const float* x     = (const float*)d_in[0];   // [1, 2048, 1739]
  const float* Wih_e = (const float*)d_in[2];   // [768, 1739]
  const float* Whh_e = (const float*)d_in[3];   // [768, 256]
  const float* bih_e = (const float*)d_in[4];   // [768]
  const float* bhh_e = (const float*)d_in[5];   // [768]
  const float* Wih_d = (const float*)d_in[6];
  const float* Whh_d = (const float*)d_in[7];
  const float* bih_d = (const float*)d_in[8];
  const float* bhh_d = (const float*)d_in[9];
  const float* Wout  = (const float*)d_in[10];  // [1739, 256]
  const float* bout  = (const float*)d_in[11];  // [1739]
  float* out = (float*)d_out;                   // [2048, 1, 1739]

  float* ws = (float*)d_ws;
  float* xpe  = ws;                              // 2048*768
  float* xpd  = xpe + (size_t)TT * H3;           // 2048*768
  float* hs   = xpd + (size_t)TT * H3;           // 2048*256
  float* henc = hs + (size_t)TT * HN;            // 256

  dim3 blk(256);
  // x-projections (b_hh folded in for r,z rows; n rows get b_ih only)
  gemm_abt<<<dim3(12, 32), blk, 0, stream>>>(x, TT, II, Wih_e, H3, bih_e, bhh_e, 2 * HN, xpe);
  gemm_abt<<<dim3(12, 32), blk, 0, stream>>>(x, TT, II, Wih_d, H3, bih_d, bhh_d, 2 * HN, xpd);
  // encoder scan -> henc
  gru_seq<<<1, 512, 0, stream>>>(xpe, Whh_e, bhh_e, nullptr, nullptr, henc);
  // decoder scan -> hs
  gru_seq<<<1, 512, 0, stream>>>(xpd, Whh_d, bhh_d, henc, hs, nullptr);
  // output projection
  gemm_abt<<<dim3(28, 32), blk, 0, stream>>>(hs, TT, HN, Wout, II, bout, nullptr, 0, out);
}